// Round 5
// baseline (1275.422 us; speedup 1.0000x reference)
//
#include <hip/hip_runtime.h>
#include <hip/hip_bf16.h>
#include <math.h>

// Problem constants: V=96, D=128, T=64, H=8, HD=16, FF=512, L=4, B=4096
#define NTHR 512

typedef __attribute__((ext_vector_type(8))) short bf16x8;
typedef __attribute__((ext_vector_type(4))) short bf16x4;
typedef __attribute__((ext_vector_type(4))) float f32x4;

#define MFMA32(a, b, c) __builtin_amdgcn_mfma_f32_16x16x32_bf16((a), (b), (c), 0, 0, 0)

#if defined(__has_builtin)
#if __has_builtin(__builtin_amdgcn_mfma_f32_16x16x16bf16_1k)
#define HAVE_MFMA16 1
#endif
#endif
#ifdef HAVE_MFMA16
#define MFMA16(a, b, c) __builtin_amdgcn_mfma_f32_16x16x16bf16_1k((a), (b), (c), 0, 0, 0)
#else
__device__ __forceinline__ f32x4 mfma16_fb(bf16x4 a, bf16x4 b, f32x4 c) {
  asm volatile("s_nop 1\n\tv_mfma_f32_16x16x16_bf16 %0, %1, %2, %0\n\ts_nop 7\n\ts_nop 7"
               : "+v"(c) : "v"(a), "v"(b));
  return c;
}
#define MFMA16(a, b, c) mfma16_fb((a), (b), (c))
#endif

// ---- workspace layout (bf16 element offsets) ----
// weights pre-converted to bf16, swizzled [K/8][N][8]: dst[(k>>3)*N*8 + n*8 + (k&7)] = W[n][k]
#define WS_EMB 0                      // [96][128]
#define WS_WQ  12288                  // 4x[128][128]
#define WS_WK  (WS_WQ + 65536)
#define WS_WV  (WS_WK + 65536)
#define WS_WO  (WS_WV + 65536)
#define WS_W1  (WS_WO + 65536)        // 4x[512][128]
#define WS_W2  (WS_W1 + 262144)       // 4x[128][512]
#define WS_END (WS_W2 + 262144)

__device__ __forceinline__ short f2bf(float f) {
  union { __hip_bfloat16 h; unsigned short s; } u;
  u.h = __float2bfloat16(f);
  return (short)u.s;
}
__device__ __forceinline__ bf16x4 pk4(f32x4 v) {
  bf16x4 r;
  r[0] = f2bf(v[0]); r[1] = f2bf(v[1]); r[2] = f2bf(v[2]); r[3] = f2bf(v[3]);
  return r;
}
__device__ __forceinline__ float gelu1(float x) {
  float y = x * __builtin_fmaf(0.0356774081f, x * x, 0.7978845608f);
  return x * __builtin_amdgcn_rcpf(1.f + exp2f(-2.885390082f * y));
}

__global__ void prep_weights(const float* __restrict__ tok_emb,
                             const float* __restrict__ Wq, const float* __restrict__ Wk,
                             const float* __restrict__ Wv, const float* __restrict__ Wo,
                             const float* __restrict__ W1, const float* __restrict__ W2,
                             short* __restrict__ wsb) {
  int i = blockIdx.x * NTHR + threadIdx.x;
  if (i < 12288) {                       // tok_emb [96][128]
    int n = i >> 7, k = i & 127;
    wsb[WS_EMB + (k >> 3) * 768 + n * 8 + (k & 7)] = f2bf(tok_emb[i]);
    return;
  }
  i -= 12288;
  if (i < 262144) {                      // Wq,Wk,Wv,Wo: [4][128][128] each
    int tensor = i >> 16;
    int rem = i & 65535;
    int l = rem >> 14;
    int w = rem & 16383;
    int n = w >> 7, k = w & 127;
    const float* src = tensor == 0 ? Wq : tensor == 1 ? Wk : tensor == 2 ? Wv : Wo;
    wsb[WS_WQ + tensor * 65536 + l * 16384 + (k >> 3) * 1024 + n * 8 + (k & 7)] =
        f2bf(src[rem]);
    return;
  }
  i -= 262144;
  if (i < 262144) {                      // W1 [4][512][128]
    int l = i >> 16;
    int w = i & 65535;
    int n = w >> 7, k = w & 127;
    wsb[WS_W1 + l * 65536 + (k >> 3) * 4096 + n * 8 + (k & 7)] = f2bf(W1[i]);
    return;
  }
  i -= 262144;
  if (i < 262144) {                      // W2 [4][128][512]
    int l = i >> 16;
    int w = i & 65535;
    int n = w >> 9, k = w & 511;
    wsb[WS_W2 + l * 65536 + (k >> 3) * 1024 + n * 8 + (k & 7)] = f2bf(W2[i]);
  }
}

// LN on register-resident residual x[4] (x[n][r] = X^T[dim wave*16+lg*4+r][token 16n+lr]).
// Cross-wave stats via sPart[8][64] (s,s2). Writes normalized bf16 to sXn[64][136].
__device__ __forceinline__ void ln_regs(const f32x4* x, const float* __restrict__ g,
                                        const float* __restrict__ bb,
                                        short* __restrict__ sXn, float* __restrict__ sPart,
                                        int wave, int lr, int lg) {
  float s[4], s2[4];
#pragma unroll
  for (int n = 0; n < 4; ++n) {
    s[n] = (x[n][0] + x[n][1]) + (x[n][2] + x[n][3]);
    s2[n] = (x[n][0] * x[n][0] + x[n][1] * x[n][1]) +
            (x[n][2] * x[n][2] + x[n][3] * x[n][3]);
  }
#pragma unroll
  for (int n = 0; n < 4; ++n) {
    s[n] += __shfl_xor(s[n], 16, 64);  s[n] += __shfl_xor(s[n], 32, 64);
    s2[n] += __shfl_xor(s2[n], 16, 64); s2[n] += __shfl_xor(s2[n], 32, 64);
  }
  if (lg == 0) {
#pragma unroll
    for (int n = 0; n < 4; ++n) {
      float2 p; p.x = s[n]; p.y = s2[n];
      *(float2*)(sPart + (wave * 64 + 16 * n + lr) * 2) = p;
    }
  }
  __syncthreads();
  int dbase = wave * 16 + lg * 4;
  f32x4 g4 = *(const f32x4*)(g + dbase);
  f32x4 b4 = *(const f32x4*)(bb + dbase);
#pragma unroll
  for (int n = 0; n < 4; ++n) {
    float S = 0.f, S2 = 0.f;
#pragma unroll
    for (int w = 0; w < 8; ++w) {
      float2 p = *(const float2*)(sPart + (w * 64 + 16 * n + lr) * 2);
      S += p.x; S2 += p.y;
    }
    float mean = S * 0.0078125f;
    float rstd = rsqrtf(__builtin_fmaf(-mean, mean, S2 * 0.0078125f) + 1e-5f);
    f32x4 o;
#pragma unroll
    for (int c = 0; c < 4; ++c) o[c] = __builtin_fmaf((x[n][c] - mean) * rstd, g4[c], b4[c]);
    *(bf16x4*)(sXn + (16 * n + lr) * 136 + dbase) = pk4(o);
  }
  __syncthreads();
}

// One block per sequence, 8 waves, wave = head. Residual X^T lives in registers.
// Occupancy economics: a block needs 2 waves/SIMD, so 2 blocks/CU requires
// TOTAL (arch+acc, unified file) regs <= 512/4 = 128. Round 4 peaked at
// ~92 arch + 48 acc ≈ 140 -> 3 waves/SIMD -> 1 block/CU. Fix: peak acc
// reduced to 32 (QKV split into 3 passes, FF1 split per-g) + waves_per_eu(4).
__global__ __launch_bounds__(512)
__attribute__((amdgpu_waves_per_eu(4, 8)))
void lm_forward(const int* __restrict__ idx, const int* __restrict__ targets,
                const float* __restrict__ tok_emb, const float* __restrict__ pos_emb,
                const float* __restrict__ bo, const float* __restrict__ ln1_g,
                const float* __restrict__ ln1_b, const float* __restrict__ ln2_g,
                const float* __restrict__ ln2_b, const float* __restrict__ b1,
                const float* __restrict__ b2, const float* __restrict__ lnf_g,
                const float* __restrict__ lnf_b, const float* __restrict__ lm_b,
                const short* __restrict__ wsb, float* __restrict__ out,
                float* __restrict__ loss_part) {
  __shared__ __align__(16) short sXn[64 * 136];   // 17408 B
  __shared__ __align__(16) short sH[64 * 264];    // 33792 B (sAtt aliases first 17408 B)
  __shared__ __align__(16) float sPart[8 * 64 * 2]; // 4096 B
  __shared__ float sTgt[64];                      // 256 B
  short* sAtt = sH;

  const int b = blockIdx.x;
  const int tid = threadIdx.x;
  const int wave = tid >> 6;
  const int lane = tid & 63;
  const int lr = lane & 15;
  const int lg = lane >> 4;
  const int dbase = wave * 16 + lg * 4;
  const f32x4 fz = {0.f, 0.f, 0.f, 0.f};
  const float KSC = 0.360673760f;                 // 0.25 * log2(e)

  // ---- embedding: residual regs ----
  f32x4 x[4];
#pragma unroll
  for (int n = 0; n < 4; ++n) {
    int t = 16 * n + lr;
    int tk = idx[b * 64 + t];
    f32x4 te = *(const f32x4*)(tok_emb + tk * 128 + dbase);
    f32x4 pe = *(const f32x4*)(pos_emb + t * 128 + dbase);
    x[n] = te + pe;
  }

#pragma unroll 1
  for (int l = 0; l < 4; ++l) {
    ln_regs(x, ln1_g + l * 128, ln1_b + l * 128, sXn, sPart, wave, lr, lg);

    // ---- QKV: three passes (16 acc each). Q,K transposed orientation; V normal ----
    const short* wq = wsb + WS_WQ + l * 16384;
    const short* wk = wsb + WS_WK + l * 16384;
    const short* wv = wsb + WS_WV + l * 16384;
    bf16x4 qf[4], kf[4], vf[4];
    {
      f32x4 aq[4];
#pragma unroll
      for (int n = 0; n < 4; ++n) aq[n] = fz;
#pragma unroll
      for (int ks = 0; ks < 4; ++ks) {
        bf16x8 qw = *(const bf16x8*)(wq + (ks * 4 + lg) * 1024 + (wave * 16 + lr) * 8);
#pragma unroll
        for (int n = 0; n < 4; ++n) {
          bf16x8 xf = *(const bf16x8*)(sXn + (16 * n + lr) * 136 + ks * 32 + lg * 8);
          aq[n] = MFMA32(qw, xf, aq[n]);
        }
      }
#pragma unroll
      for (int n = 0; n < 4; ++n) qf[n] = pk4(aq[n] * KSC);
    }
    {
      f32x4 ak[4];
#pragma unroll
      for (int n = 0; n < 4; ++n) ak[n] = fz;
#pragma unroll
      for (int ks = 0; ks < 4; ++ks) {
        bf16x8 kw = *(const bf16x8*)(wk + (ks * 4 + lg) * 1024 + (wave * 16 + lr) * 8);
#pragma unroll
        for (int n = 0; n < 4; ++n) {
          bf16x8 xf = *(const bf16x8*)(sXn + (16 * n + lr) * 136 + ks * 32 + lg * 8);
          ak[n] = MFMA32(kw, xf, ak[n]);
        }
      }
#pragma unroll
      for (int n = 0; n < 4; ++n) kf[n] = pk4(ak[n]);
    }
    {
      f32x4 av[4];
#pragma unroll
      for (int n = 0; n < 4; ++n) av[n] = fz;
#pragma unroll
      for (int ks = 0; ks < 4; ++ks) {
        bf16x8 vw = *(const bf16x8*)(wv + (ks * 4 + lg) * 1024 + (wave * 16 + lr) * 8);
#pragma unroll
        for (int n = 0; n < 4; ++n) {
          bf16x8 xf = *(const bf16x8*)(sXn + (16 * n + lr) * 136 + ks * 32 + lg * 8);
          av[n] = MFMA32(xf, vw, av[n]);
        }
      }
#pragma unroll
      for (int m = 0; m < 4; ++m) vf[m] = pk4(av[m]);
    }

    // ---- attention (in-register; causal tile-skip) ----
#pragma unroll
    for (int n = 0; n < 4; ++n) {
      f32x4 sc[4];
#pragma unroll
      for (int m = 0; m < 4; ++m)
        if (m <= n) sc[m] = MFMA16(kf[m], qf[n], fz);
      // mask diagonal tile: key lg*4+r > query lr
#pragma unroll
      for (int r = 0; r < 4; ++r)
        if (lg * 4 + r > lr) sc[n][r] = -1e30f;
      float mx = -1e30f;
#pragma unroll
      for (int m = 0; m < 4; ++m)
        if (m <= n)
#pragma unroll
          for (int r = 0; r < 4; ++r) mx = fmaxf(mx, sc[m][r]);
      mx = fmaxf(mx, __shfl_xor(mx, 16, 64));
      mx = fmaxf(mx, __shfl_xor(mx, 32, 64));
      float sum = 0.f;
#pragma unroll
      for (int m = 0; m < 4; ++m)
        if (m <= n)
#pragma unroll
          for (int r = 0; r < 4; ++r) {
            float p = exp2f(sc[m][r] - mx);
            sc[m][r] = p;
            sum += p;
          }
      sum += __shfl_xor(sum, 16, 64);
      sum += __shfl_xor(sum, 32, 64);
      float rinv = __builtin_amdgcn_rcpf(sum);
      f32x4 ao = fz;
#pragma unroll
      for (int m = 0; m < 4; ++m)
        if (m <= n) {
          bf16x4 pf = pk4(sc[m] * rinv);
          ao = MFMA16(vf[m], pf, ao);
        }
      *(bf16x4*)(sAtt + (16 * n + lr) * 136 + dbase) = pk4(ao);
    }
    __syncthreads();

    // ---- Wo + residual (in regs) ----
    {
      const short* wo = wsb + WS_WO + l * 16384;
      f32x4 ac[4];
#pragma unroll
      for (int n = 0; n < 4; ++n) ac[n] = fz;
#pragma unroll
      for (int ks = 0; ks < 4; ++ks) {
        bf16x8 wf = *(const bf16x8*)(wo + (ks * 4 + lg) * 1024 + (wave * 16 + lr) * 8);
#pragma unroll
        for (int n = 0; n < 4; ++n) {
          bf16x8 af = *(const bf16x8*)(sAtt + (16 * n + lr) * 136 + ks * 32 + lg * 8);
          ac[n] = MFMA32(wf, af, ac[n]);
        }
      }
      f32x4 bo4 = *(const f32x4*)(bo + l * 128 + dbase);
#pragma unroll
      for (int n = 0; n < 4; ++n) x[n] = x[n] + ac[n] + bo4;
    }

    ln_regs(x, ln2_g + l * 128, ln2_b + l * 128, sXn, sPart, wave, lr, lg);

    // ---- FF: 2 hidden chunks of 256; FF1 per-g passes (16 acc); FF2 acc in regs ----
    {
      const short* w1 = wsb + WS_W1 + l * 65536;
      const short* w2 = wsb + WS_W2 + l * 65536;
      f32x4 a2[4];
#pragma unroll
      for (int n = 0; n < 4; ++n) a2[n] = fz;
#pragma unroll 1
      for (int c = 0; c < 2; ++c) {
#pragma unroll 1
        for (int g = 0; g < 2; ++g) {
          f32x4 a1[4];
#pragma unroll
          for (int n = 0; n < 4; ++n) a1[n] = fz;
#pragma unroll
          for (int ks = 0; ks < 4; ++ks) {
            bf16x8 w1f = *(const bf16x8*)(w1 + (ks * 4 + lg) * 4096 +
                                          (c * 256 + wave * 32 + g * 16 + lr) * 8);
#pragma unroll
            for (int n = 0; n < 4; ++n) {
              bf16x8 xf = *(const bf16x8*)(sXn + (16 * n + lr) * 136 + ks * 32 + lg * 8);
              a1[n] = MFMA32(w1f, xf, a1[n]);
            }
          }
          f32x4 b1v = *(const f32x4*)(b1 + l * 512 + c * 256 + wave * 32 + g * 16 + lg * 4);
#pragma unroll
          for (int n = 0; n < 4; ++n) {
            f32x4 hv;
#pragma unroll
            for (int r = 0; r < 4; ++r) hv[r] = gelu1(a1[n][r] + b1v[r]);
            *(bf16x4*)(sH + (16 * n + lr) * 264 + wave * 32 + g * 16 + lg * 4) = pk4(hv);
          }
        }
        __syncthreads();
#pragma unroll
        for (int ks = 0; ks < 8; ++ks) {
          bf16x8 w2f = *(const bf16x8*)(w2 + (c * 32 + ks * 4 + lg) * 1024 +
                                        (wave * 16 + lr) * 8);
#pragma unroll
          for (int n = 0; n < 4; ++n) {
            bf16x8 hf = *(const bf16x8*)(sH + (16 * n + lr) * 264 + ks * 32 + lg * 8);
            a2[n] = MFMA32(w2f, hf, a2[n]);
          }
        }
        if (c == 0) __syncthreads();
      }
      f32x4 b2v = *(const f32x4*)(b2 + l * 128 + dbase);
#pragma unroll
      for (int n = 0; n < 4; ++n) x[n] = x[n] + a2[n] + b2v;
    }
  }

  // ---- final LN ----
  ln_regs(x, lnf_g, lnf_b, sXn, sPart, wave, lr, lg);

  // ---- logits + CE partials (waves 0..5 cover 96 vocab cols) ----
  if (wave < 6) {
    f32x4 al[4];
#pragma unroll
    for (int n = 0; n < 4; ++n) al[n] = fz;
#pragma unroll
    for (int ks = 0; ks < 4; ++ks) {
      bf16x8 ef = *(const bf16x8*)(wsb + WS_EMB + (ks * 4 + lg) * 768 +
                                   (wave * 16 + lr) * 8);
#pragma unroll
      for (int n = 0; n < 4; ++n) {
        bf16x8 xf = *(const bf16x8*)(sXn + (16 * n + lr) * 136 + ks * 32 + lg * 8);
        al[n] = MFMA32(ef, xf, al[n]);
      }
    }
    f32x4 lb = *(const f32x4*)(lm_b + dbase);
#pragma unroll
    for (int n = 0; n < 4; ++n) {
      int t = 16 * n + lr;
      f32x4 v = al[n] + lb;
      *(f32x4*)(out + ((size_t)b * 64 + t) * 96 + dbase) = v;
      float mx = fmaxf(fmaxf(v[0], v[1]), fmaxf(v[2], v[3]));
      mx = fmaxf(mx, __shfl_xor(mx, 16, 64));
      mx = fmaxf(mx, __shfl_xor(mx, 32, 64));
      float es = __expf(v[0] - mx) + __expf(v[1] - mx) +
                 __expf(v[2] - mx) + __expf(v[3] - mx);
      es += __shfl_xor(es, 16, 64);
      es += __shfl_xor(es, 32, 64);
      if (lg == 0) {
        float2 p; p.x = mx; p.y = es;
        *(float2*)(sPart + (wave * 64 + t) * 2) = p;
      }
      int cgt = targets[b * 64 + t];
      if ((cgt >> 4) == wave && ((cgt >> 2) & 3) == lg) {
#pragma unroll
        for (int r = 0; r < 4; ++r)
          if ((cgt & 3) == r) sTgt[t] = v[r];
      }
    }
  }
  __syncthreads();
  if (wave == 0) {
    float mxw[6], esw[6];
#pragma unroll
    for (int w = 0; w < 6; ++w) {
      float2 p = *(const float2*)(sPart + (w * 64 + lane) * 2);
      mxw[w] = p.x; esw[w] = p.y;
    }
    float MX = mxw[0];
#pragma unroll
    for (int w = 1; w < 6; ++w) MX = fmaxf(MX, mxw[w]);
    float SUM = 0.f;
#pragma unroll
    for (int w = 0; w < 6; ++w) SUM += esw[w] * __expf(mxw[w] - MX);
    float lt = MX + logf(SUM) - sTgt[lane];
#pragma unroll
    for (int m = 32; m >= 1; m >>= 1) lt += __shfl_xor(lt, m, 64);
    if (lane == 0) loss_part[b] = lt;
  }
}

__global__ void loss_reduce(const float* __restrict__ loss_part, float* __restrict__ out_loss) {
  __shared__ float red[256];
  int t = threadIdx.x;
  float s = 0.f;
  for (int i = t; i < 4096; i += 256) s += loss_part[i];
  red[t] = s;
  __syncthreads();
  for (int k = 128; k >= 1; k >>= 1) {
    if (t < k) red[t] += red[t + k];
    __syncthreads();
  }
  if (t == 0) out_loss[0] = red[0] * (1.f / 262144.f);
}

extern "C" void kernel_launch(void* const* d_in, const int* in_sizes, int n_in,
                              void* d_out, int out_size, void* d_ws, size_t ws_size,
                              hipStream_t stream) {
  (void)in_sizes; (void)n_in; (void)ws_size;
  const int* idx      = (const int*)d_in[0];
  const int* targets  = (const int*)d_in[1];
  const float* tok_emb = (const float*)d_in[2];
  const float* pos_emb = (const float*)d_in[3];
  const float* Wq = (const float*)d_in[4];
  const float* Wk = (const float*)d_in[5];
  const float* Wv = (const float*)d_in[6];
  const float* Wo = (const float*)d_in[7];
  const float* bo = (const float*)d_in[8];
  const float* ln1_g = (const float*)d_in[9];
  const float* ln1_b = (const float*)d_in[10];
  const float* ln2_g = (const float*)d_in[11];
  const float* ln2_b = (const float*)d_in[12];
  const float* W1 = (const float*)d_in[13];
  const float* b1 = (const float*)d_in[14];
  const float* W2 = (const float*)d_in[15];
  const float* b2 = (const float*)d_in[16];
  const float* lnf_g = (const float*)d_in[17];
  const float* lnf_b = (const float*)d_in[18];
  const float* lm_b = (const float*)d_in[19];

  short* wsb = (short*)d_ws;
  float* loss_part = (float*)((char*)d_ws + (size_t)WS_END * 2);
  float* out = (float*)d_out;

  prep_weights<<<1560, NTHR, 0, stream>>>(tok_emb, Wq, Wk, Wv, Wo, W1, W2, wsb);
  lm_forward<<<4096, NTHR, 0, stream>>>(idx, targets, tok_emb, pos_emb, bo,
                                        ln1_g, ln1_b, ln2_g, ln2_b, b1, b2,
                                        lnf_g, lnf_b, lm_b, wsb, out, loss_part);
  loss_reduce<<<1, 256, 0, stream>>>(loss_part, out + (out_size - 1));
}

// Round 6
// 1272.400 us; speedup vs baseline: 1.0024x; 1.0024x over previous
//
#include <hip/hip_runtime.h>
#include <hip/hip_bf16.h>
#include <math.h>

// Problem constants: V=96, D=128, T=64, H=8, HD=16, FF=512, L=4, B=4096
#define NTHR 512

typedef __attribute__((ext_vector_type(8))) short bf16x8;
typedef __attribute__((ext_vector_type(4))) short bf16x4;
typedef __attribute__((ext_vector_type(4))) float f32x4;

#define MFMA32(a, b, c) __builtin_amdgcn_mfma_f32_16x16x32_bf16((a), (b), (c), 0, 0, 0)

#if defined(__has_builtin)
#if __has_builtin(__builtin_amdgcn_mfma_f32_16x16x16bf16_1k)
#define HAVE_MFMA16 1
#endif
#endif
#ifdef HAVE_MFMA16
#define MFMA16(a, b, c) __builtin_amdgcn_mfma_f32_16x16x16bf16_1k((a), (b), (c), 0, 0, 0)
#else
__device__ __forceinline__ f32x4 mfma16_fb(bf16x4 a, bf16x4 b, f32x4 c) {
  asm volatile("s_nop 1\n\tv_mfma_f32_16x16x16_bf16 %0, %1, %2, %0\n\ts_nop 7\n\ts_nop 7"
               : "+v"(c) : "v"(a), "v"(b));
  return c;
}
#define MFMA16(a, b, c) mfma16_fb((a), (b), (c))
#endif

// ---- workspace layout (bf16 element offsets) ----
// weights pre-converted to bf16, swizzled [K/8][N][8]: dst[(k>>3)*N*8 + n*8 + (k&7)] = W[n][k]
#define WS_EMB 0                      // [96][128]
#define WS_WQ  12288                  // 4x[128][128]
#define WS_WK  (WS_WQ + 65536)
#define WS_WV  (WS_WK + 65536)
#define WS_WO  (WS_WV + 65536)
#define WS_W1  (WS_WO + 65536)        // 4x[512][128]
#define WS_W2  (WS_W1 + 262144)       // 4x[128][512]
#define WS_END (WS_W2 + 262144)

__device__ __forceinline__ short f2bf(float f) {
  union { __hip_bfloat16 h; unsigned short s; } u;
  u.h = __float2bfloat16(f);
  return (short)u.s;
}
__device__ __forceinline__ bf16x4 pk4(f32x4 v) {
  bf16x4 r;
  r[0] = f2bf(v[0]); r[1] = f2bf(v[1]); r[2] = f2bf(v[2]); r[3] = f2bf(v[3]);
  return r;
}
__device__ __forceinline__ float gelu1(float x) {
  float y = x * __builtin_fmaf(0.0356774081f, x * x, 0.7978845608f);
  return x * __builtin_amdgcn_rcpf(1.f + exp2f(-2.885390082f * y));
}

__global__ void prep_weights(const float* __restrict__ tok_emb,
                             const float* __restrict__ Wq, const float* __restrict__ Wk,
                             const float* __restrict__ Wv, const float* __restrict__ Wo,
                             const float* __restrict__ W1, const float* __restrict__ W2,
                             short* __restrict__ wsb) {
  int i = blockIdx.x * NTHR + threadIdx.x;
  if (i < 12288) {                       // tok_emb [96][128]
    int n = i >> 7, k = i & 127;
    wsb[WS_EMB + (k >> 3) * 768 + n * 8 + (k & 7)] = f2bf(tok_emb[i]);
    return;
  }
  i -= 12288;
  if (i < 262144) {                      // Wq,Wk,Wv,Wo: [4][128][128] each
    int tensor = i >> 16;
    int rem = i & 65535;
    int l = rem >> 14;
    int w = rem & 16383;
    int n = w >> 7, k = w & 127;
    const float* src = tensor == 0 ? Wq : tensor == 1 ? Wk : tensor == 2 ? Wv : Wo;
    wsb[WS_WQ + tensor * 65536 + l * 16384 + (k >> 3) * 1024 + n * 8 + (k & 7)] =
        f2bf(src[rem]);
    return;
  }
  i -= 262144;
  if (i < 262144) {                      // W1 [4][512][128]
    int l = i >> 16;
    int w = i & 65535;
    int n = w >> 7, k = w & 127;
    wsb[WS_W1 + l * 65536 + (k >> 3) * 4096 + n * 8 + (k & 7)] = f2bf(W1[i]);
    return;
  }
  i -= 262144;
  if (i < 262144) {                      // W2 [4][128][512]
    int l = i >> 16;
    int w = i & 65535;
    int n = w >> 9, k = w & 511;
    wsb[WS_W2 + l * 65536 + (k >> 3) * 1024 + n * 8 + (k & 7)] = f2bf(W2[i]);
  }
}

// LN on register-resident residual x[4] (x[n][r] = X^T[dim wave*16+lg*4+r][token 16n+lr]).
// Cross-wave stats via sPart[8][64] (s,s2). Writes normalized bf16 to sXn[64][136].
__device__ __forceinline__ void ln_regs(const f32x4* x, const float* __restrict__ g,
                                        const float* __restrict__ bb,
                                        short* __restrict__ sXn, float* __restrict__ sPart,
                                        int wave, int lr, int lg) {
  float s[4], s2[4];
#pragma unroll
  for (int n = 0; n < 4; ++n) {
    s[n] = (x[n][0] + x[n][1]) + (x[n][2] + x[n][3]);
    s2[n] = (x[n][0] * x[n][0] + x[n][1] * x[n][1]) +
            (x[n][2] * x[n][2] + x[n][3] * x[n][3]);
  }
#pragma unroll
  for (int n = 0; n < 4; ++n) {
    s[n] += __shfl_xor(s[n], 16, 64);  s[n] += __shfl_xor(s[n], 32, 64);
    s2[n] += __shfl_xor(s2[n], 16, 64); s2[n] += __shfl_xor(s2[n], 32, 64);
  }
  if (lg == 0) {
#pragma unroll
    for (int n = 0; n < 4; ++n) {
      float2 p; p.x = s[n]; p.y = s2[n];
      *(float2*)(sPart + (wave * 64 + 16 * n + lr) * 2) = p;
    }
  }
  __syncthreads();
  int dbase = wave * 16 + lg * 4;
  f32x4 g4 = *(const f32x4*)(g + dbase);
  f32x4 b4 = *(const f32x4*)(bb + dbase);
#pragma unroll
  for (int n = 0; n < 4; ++n) {
    float S = 0.f, S2 = 0.f;
#pragma unroll
    for (int w = 0; w < 8; ++w) {
      float2 p = *(const float2*)(sPart + (w * 64 + 16 * n + lr) * 2);
      S += p.x; S2 += p.y;
    }
    float mean = S * 0.0078125f;
    float rstd = rsqrtf(__builtin_fmaf(-mean, mean, S2 * 0.0078125f) + 1e-5f);
    f32x4 o;
#pragma unroll
    for (int c = 0; c < 4; ++c) o[c] = __builtin_fmaf((x[n][c] - mean) * rstd, g4[c], b4[c]);
    *(bf16x4*)(sXn + (16 * n + lr) * 136 + dbase) = pk4(o);
  }
  __syncthreads();
}

// One block per sequence, 8 waves, wave = head. Residual X^T lives in registers.
// Register economics (2048 regs/CU): 2 blocks/CU (16 waves) requires TOTAL
// (arch+acc, unified file) <= 128/wave. Evidence: R4 (512,2) -> 92 arch + 48 acc
// = 140 -> 1 block. R5 waves_per_eu(4,8) -> budget from MAX (8/EU) = 64 -> spills.
// Here: waves_per_eu(4,4) -> budget 128 total; peak acc demand trimmed to 32
// (3-pass QKV, per-g FF1) so natural demand ~124 fits.
__global__ __launch_bounds__(512)
__attribute__((amdgpu_waves_per_eu(4, 4)))
void lm_forward(const int* __restrict__ idx, const int* __restrict__ targets,
                const float* __restrict__ tok_emb, const float* __restrict__ pos_emb,
                const float* __restrict__ bo, const float* __restrict__ ln1_g,
                const float* __restrict__ ln1_b, const float* __restrict__ ln2_g,
                const float* __restrict__ ln2_b, const float* __restrict__ b1,
                const float* __restrict__ b2, const float* __restrict__ lnf_g,
                const float* __restrict__ lnf_b, const float* __restrict__ lm_b,
                const short* __restrict__ wsb, float* __restrict__ out,
                float* __restrict__ loss_part) {
  __shared__ __align__(16) short sXn[64 * 136];   // 17408 B
  __shared__ __align__(16) short sH[64 * 264];    // 33792 B (sAtt aliases first 17408 B)
  __shared__ __align__(16) float sPart[8 * 64 * 2]; // 4096 B
  __shared__ float sTgt[64];                      // 256 B
  short* sAtt = sH;

  const int b = blockIdx.x;
  const int tid = threadIdx.x;
  const int wave = tid >> 6;
  const int lane = tid & 63;
  const int lr = lane & 15;
  const int lg = lane >> 4;
  const int dbase = wave * 16 + lg * 4;
  const f32x4 fz = {0.f, 0.f, 0.f, 0.f};
  const float KSC = 0.360673760f;                 // 0.25 * log2(e)

  // ---- embedding: residual regs ----
  f32x4 x[4];
#pragma unroll
  for (int n = 0; n < 4; ++n) {
    int t = 16 * n + lr;
    int tk = idx[b * 64 + t];
    f32x4 te = *(const f32x4*)(tok_emb + tk * 128 + dbase);
    f32x4 pe = *(const f32x4*)(pos_emb + t * 128 + dbase);
    x[n] = te + pe;
  }

#pragma unroll 1
  for (int l = 0; l < 4; ++l) {
    ln_regs(x, ln1_g + l * 128, ln1_b + l * 128, sXn, sPart, wave, lr, lg);

    // ---- QKV: three passes (16 acc each). Q,K transposed orientation; V normal ----
    const short* wq = wsb + WS_WQ + l * 16384;
    const short* wk = wsb + WS_WK + l * 16384;
    const short* wv = wsb + WS_WV + l * 16384;
    bf16x4 qf[4], kf[4], vf[4];
    {
      f32x4 aq[4];
#pragma unroll
      for (int n = 0; n < 4; ++n) aq[n] = fz;
#pragma unroll
      for (int ks = 0; ks < 4; ++ks) {
        bf16x8 qw = *(const bf16x8*)(wq + (ks * 4 + lg) * 1024 + (wave * 16 + lr) * 8);
#pragma unroll
        for (int n = 0; n < 4; ++n) {
          bf16x8 xf = *(const bf16x8*)(sXn + (16 * n + lr) * 136 + ks * 32 + lg * 8);
          aq[n] = MFMA32(qw, xf, aq[n]);
        }
      }
#pragma unroll
      for (int n = 0; n < 4; ++n) qf[n] = pk4(aq[n] * KSC);
    }
    {
      f32x4 ak[4];
#pragma unroll
      for (int n = 0; n < 4; ++n) ak[n] = fz;
#pragma unroll
      for (int ks = 0; ks < 4; ++ks) {
        bf16x8 kw = *(const bf16x8*)(wk + (ks * 4 + lg) * 1024 + (wave * 16 + lr) * 8);
#pragma unroll
        for (int n = 0; n < 4; ++n) {
          bf16x8 xf = *(const bf16x8*)(sXn + (16 * n + lr) * 136 + ks * 32 + lg * 8);
          ak[n] = MFMA32(kw, xf, ak[n]);
        }
      }
#pragma unroll
      for (int n = 0; n < 4; ++n) kf[n] = pk4(ak[n]);
    }
    {
      f32x4 av[4];
#pragma unroll
      for (int n = 0; n < 4; ++n) av[n] = fz;
#pragma unroll
      for (int ks = 0; ks < 4; ++ks) {
        bf16x8 vw = *(const bf16x8*)(wv + (ks * 4 + lg) * 1024 + (wave * 16 + lr) * 8);
#pragma unroll
        for (int n = 0; n < 4; ++n) {
          bf16x8 xf = *(const bf16x8*)(sXn + (16 * n + lr) * 136 + ks * 32 + lg * 8);
          av[n] = MFMA32(xf, vw, av[n]);
        }
      }
#pragma unroll
      for (int m = 0; m < 4; ++m) vf[m] = pk4(av[m]);
    }

    // ---- attention (in-register; causal tile-skip) ----
#pragma unroll
    for (int n = 0; n < 4; ++n) {
      f32x4 sc[4];
#pragma unroll
      for (int m = 0; m < 4; ++m)
        if (m <= n) sc[m] = MFMA16(kf[m], qf[n], fz);
      // mask diagonal tile: key lg*4+r > query lr
#pragma unroll
      for (int r = 0; r < 4; ++r)
        if (lg * 4 + r > lr) sc[n][r] = -1e30f;
      float mx = -1e30f;
#pragma unroll
      for (int m = 0; m < 4; ++m)
        if (m <= n)
#pragma unroll
          for (int r = 0; r < 4; ++r) mx = fmaxf(mx, sc[m][r]);
      mx = fmaxf(mx, __shfl_xor(mx, 16, 64));
      mx = fmaxf(mx, __shfl_xor(mx, 32, 64));
      float sum = 0.f;
#pragma unroll
      for (int m = 0; m < 4; ++m)
        if (m <= n)
#pragma unroll
          for (int r = 0; r < 4; ++r) {
            float p = exp2f(sc[m][r] - mx);
            sc[m][r] = p;
            sum += p;
          }
      sum += __shfl_xor(sum, 16, 64);
      sum += __shfl_xor(sum, 32, 64);
      float rinv = __builtin_amdgcn_rcpf(sum);
      f32x4 ao = fz;
#pragma unroll
      for (int m = 0; m < 4; ++m)
        if (m <= n) {
          bf16x4 pf = pk4(sc[m] * rinv);
          ao = MFMA16(vf[m], pf, ao);
        }
      *(bf16x4*)(sAtt + (16 * n + lr) * 136 + dbase) = pk4(ao);
    }
    __syncthreads();

    // ---- Wo + residual (in regs) ----
    {
      const short* wo = wsb + WS_WO + l * 16384;
      f32x4 ac[4];
#pragma unroll
      for (int n = 0; n < 4; ++n) ac[n] = fz;
#pragma unroll
      for (int ks = 0; ks < 4; ++ks) {
        bf16x8 wf = *(const bf16x8*)(wo + (ks * 4 + lg) * 1024 + (wave * 16 + lr) * 8);
#pragma unroll
        for (int n = 0; n < 4; ++n) {
          bf16x8 af = *(const bf16x8*)(sAtt + (16 * n + lr) * 136 + ks * 32 + lg * 8);
          ac[n] = MFMA32(wf, af, ac[n]);
        }
      }
      f32x4 bo4 = *(const f32x4*)(bo + l * 128 + dbase);
#pragma unroll
      for (int n = 0; n < 4; ++n) x[n] = x[n] + ac[n] + bo4;
    }

    ln_regs(x, ln2_g + l * 128, ln2_b + l * 128, sXn, sPart, wave, lr, lg);

    // ---- FF: 2 hidden chunks of 256; FF1 per-g passes (16 acc); FF2 acc in regs ----
    {
      const short* w1 = wsb + WS_W1 + l * 65536;
      const short* w2 = wsb + WS_W2 + l * 65536;
      f32x4 a2[4];
#pragma unroll
      for (int n = 0; n < 4; ++n) a2[n] = fz;
#pragma unroll 1
      for (int c = 0; c < 2; ++c) {
#pragma unroll 1
        for (int g = 0; g < 2; ++g) {
          f32x4 a1[4];
#pragma unroll
          for (int n = 0; n < 4; ++n) a1[n] = fz;
#pragma unroll
          for (int ks = 0; ks < 4; ++ks) {
            bf16x8 w1f = *(const bf16x8*)(w1 + (ks * 4 + lg) * 4096 +
                                          (c * 256 + wave * 32 + g * 16 + lr) * 8);
#pragma unroll
            for (int n = 0; n < 4; ++n) {
              bf16x8 xf = *(const bf16x8*)(sXn + (16 * n + lr) * 136 + ks * 32 + lg * 8);
              a1[n] = MFMA32(w1f, xf, a1[n]);
            }
          }
          f32x4 b1v = *(const f32x4*)(b1 + l * 512 + c * 256 + wave * 32 + g * 16 + lg * 4);
#pragma unroll
          for (int n = 0; n < 4; ++n) {
            f32x4 hv;
#pragma unroll
            for (int r = 0; r < 4; ++r) hv[r] = gelu1(a1[n][r] + b1v[r]);
            *(bf16x4*)(sH + (16 * n + lr) * 264 + wave * 32 + g * 16 + lg * 4) = pk4(hv);
          }
        }
        __syncthreads();
#pragma unroll
        for (int ks = 0; ks < 8; ++ks) {
          bf16x8 w2f = *(const bf16x8*)(w2 + (c * 32 + ks * 4 + lg) * 1024 +
                                        (wave * 16 + lr) * 8);
#pragma unroll
          for (int n = 0; n < 4; ++n) {
            bf16x8 hf = *(const bf16x8*)(sH + (16 * n + lr) * 264 + ks * 32 + lg * 8);
            a2[n] = MFMA32(w2f, hf, a2[n]);
          }
        }
        if (c == 0) __syncthreads();
      }
      f32x4 b2v = *(const f32x4*)(b2 + l * 128 + dbase);
#pragma unroll
      for (int n = 0; n < 4; ++n) x[n] = x[n] + a2[n] + b2v;
    }
  }

  // ---- final LN ----
  ln_regs(x, lnf_g, lnf_b, sXn, sPart, wave, lr, lg);

  // ---- logits + CE partials (waves 0..5 cover 96 vocab cols) ----
  if (wave < 6) {
    f32x4 al[4];
#pragma unroll
    for (int n = 0; n < 4; ++n) al[n] = fz;
#pragma unroll
    for (int ks = 0; ks < 4; ++ks) {
      bf16x8 ef = *(const bf16x8*)(wsb + WS_EMB + (ks * 4 + lg) * 768 +
                                   (wave * 16 + lr) * 8);
#pragma unroll
      for (int n = 0; n < 4; ++n) {
        bf16x8 xf = *(const bf16x8*)(sXn + (16 * n + lr) * 136 + ks * 32 + lg * 8);
        al[n] = MFMA32(ef, xf, al[n]);
      }
    }
    f32x4 lb = *(const f32x4*)(lm_b + dbase);
#pragma unroll
    for (int n = 0; n < 4; ++n) {
      int t = 16 * n + lr;
      f32x4 v = al[n] + lb;
      *(f32x4*)(out + ((size_t)b * 64 + t) * 96 + dbase) = v;
      float mx = fmaxf(fmaxf(v[0], v[1]), fmaxf(v[2], v[3]));
      mx = fmaxf(mx, __shfl_xor(mx, 16, 64));
      mx = fmaxf(mx, __shfl_xor(mx, 32, 64));
      float es = __expf(v[0] - mx) + __expf(v[1] - mx) +
                 __expf(v[2] - mx) + __expf(v[3] - mx);
      es += __shfl_xor(es, 16, 64);
      es += __shfl_xor(es, 32, 64);
      if (lg == 0) {
        float2 p; p.x = mx; p.y = es;
        *(float2*)(sPart + (wave * 64 + t) * 2) = p;
      }
      int cgt = targets[b * 64 + t];
      if ((cgt >> 4) == wave && ((cgt >> 2) & 3) == lg) {
#pragma unroll
        for (int r = 0; r < 4; ++r)
          if ((cgt & 3) == r) sTgt[t] = v[r];
      }
    }
  }
  __syncthreads();
  if (wave == 0) {
    float mxw[6], esw[6];
#pragma unroll
    for (int w = 0; w < 6; ++w) {
      float2 p = *(const float2*)(sPart + (w * 64 + lane) * 2);
      mxw[w] = p.x; esw[w] = p.y;
    }
    float MX = mxw[0];
#pragma unroll
    for (int w = 1; w < 6; ++w) MX = fmaxf(MX, mxw[w]);
    float SUM = 0.f;
#pragma unroll
    for (int w = 0; w < 6; ++w) SUM += esw[w] * __expf(mxw[w] - MX);
    float lt = MX + logf(SUM) - sTgt[lane];
#pragma unroll
    for (int m = 32; m >= 1; m >>= 1) lt += __shfl_xor(lt, m, 64);
    if (lane == 0) loss_part[b] = lt;
  }
}

__global__ void loss_reduce(const float* __restrict__ loss_part, float* __restrict__ out_loss) {
  __shared__ float red[256];
  int t = threadIdx.x;
  float s = 0.f;
  for (int i = t; i < 4096; i += 256) s += loss_part[i];
  red[t] = s;
  __syncthreads();
  for (int k = 128; k >= 1; k >>= 1) {
    if (t < k) red[t] += red[t + k];
    __syncthreads();
  }
  if (t == 0) out_loss[0] = red[0] * (1.f / 262144.f);
}

extern "C" void kernel_launch(void* const* d_in, const int* in_sizes, int n_in,
                              void* d_out, int out_size, void* d_ws, size_t ws_size,
                              hipStream_t stream) {
  (void)in_sizes; (void)n_in; (void)ws_size;
  const int* idx      = (const int*)d_in[0];
  const int* targets  = (const int*)d_in[1];
  const float* tok_emb = (const float*)d_in[2];
  const float* pos_emb = (const float*)d_in[3];
  const float* Wq = (const float*)d_in[4];
  const float* Wk = (const float*)d_in[5];
  const float* Wv = (const float*)d_in[6];
  const float* Wo = (const float*)d_in[7];
  const float* bo = (const float*)d_in[8];
  const float* ln1_g = (const float*)d_in[9];
  const float* ln1_b = (const float*)d_in[10];
  const float* ln2_g = (const float*)d_in[11];
  const float* ln2_b = (const float*)d_in[12];
  const float* W1 = (const float*)d_in[13];
  const float* b1 = (const float*)d_in[14];
  const float* W2 = (const float*)d_in[15];
  const float* b2 = (const float*)d_in[16];
  const float* lnf_g = (const float*)d_in[17];
  const float* lnf_b = (const float*)d_in[18];
  const float* lm_b = (const float*)d_in[19];

  short* wsb = (short*)d_ws;
  float* loss_part = (float*)((char*)d_ws + (size_t)WS_END * 2);
  float* out = (float*)d_out;

  prep_weights<<<1560, NTHR, 0, stream>>>(tok_emb, Wq, Wk, Wv, Wo, W1, W2, wsb);
  lm_forward<<<4096, NTHR, 0, stream>>>(idx, targets, tok_emb, pos_emb, bo,
                                        ln1_g, ln1_b, ln2_g, ln2_b, b1, b2,
                                        lnf_g, lnf_b, lm_b, wsb, out, loss_part);
  loss_reduce<<<1, 256, 0, stream>>>(loss_part, out + (out_size - 1));
}

// Round 7
// 988.388 us; speedup vs baseline: 1.2904x; 1.2873x over previous
//
#include <hip/hip_runtime.h>
#include <hip/hip_bf16.h>
#include <math.h>

// Problem constants: V=96, D=128, T=64, H=8, HD=16, FF=512, L=4, B=4096
#define NTHR 512

typedef __attribute__((ext_vector_type(8))) short bf16x8;
typedef __attribute__((ext_vector_type(4))) short bf16x4;
typedef __attribute__((ext_vector_type(4))) float f32x4;

#define MFMA32(a, b, c) __builtin_amdgcn_mfma_f32_16x16x32_bf16((a), (b), (c), 0, 0, 0)

#if defined(__has_builtin)
#if __has_builtin(__builtin_amdgcn_mfma_f32_16x16x16bf16_1k)
#define HAVE_MFMA16 1
#endif
#endif
#ifdef HAVE_MFMA16
#define MFMA16(a, b, c) __builtin_amdgcn_mfma_f32_16x16x16bf16_1k((a), (b), (c), 0, 0, 0)
#else
__device__ __forceinline__ f32x4 mfma16_fb(bf16x4 a, bf16x4 b, f32x4 c) {
  asm volatile("s_nop 1\n\tv_mfma_f32_16x16x16_bf16 %0, %1, %2, %0\n\ts_nop 7\n\ts_nop 7"
               : "+v"(c) : "v"(a), "v"(b));
  return c;
}
#define MFMA16(a, b, c) mfma16_fb((a), (b), (c))
#endif

// ---- workspace layout (bf16 element offsets) ----
// weights pre-converted to bf16, swizzled [K/8][N][8]: dst[(k>>3)*N*8 + n*8 + (k&7)] = W[n][k]
#define WS_EMB 0                      // [96][128]
#define WS_WQ  12288                  // 4x[128][128]
#define WS_WK  (WS_WQ + 65536)
#define WS_WV  (WS_WK + 65536)
#define WS_WO  (WS_WV + 65536)
#define WS_W1  (WS_WO + 65536)        // 4x[512][128]
#define WS_W2  (WS_W1 + 262144)       // 4x[128][512]
#define WS_END (WS_W2 + 262144)

__device__ __forceinline__ short f2bf(float f) {
  union { __hip_bfloat16 h; unsigned short s; } u;
  u.h = __float2bfloat16(f);
  return (short)u.s;
}
__device__ __forceinline__ bf16x4 pk4(f32x4 v) {
  bf16x4 r;
  r[0] = f2bf(v[0]); r[1] = f2bf(v[1]); r[2] = f2bf(v[2]); r[3] = f2bf(v[3]);
  return r;
}
__device__ __forceinline__ float gelu1(float x) {
  float y = x * __builtin_fmaf(0.0356774081f, x * x, 0.7978845608f);
  return x * __builtin_amdgcn_rcpf(1.f + exp2f(-2.885390082f * y));
}

__global__ void prep_weights(const float* __restrict__ tok_emb,
                             const float* __restrict__ Wq, const float* __restrict__ Wk,
                             const float* __restrict__ Wv, const float* __restrict__ Wo,
                             const float* __restrict__ W1, const float* __restrict__ W2,
                             short* __restrict__ wsb) {
  int i = blockIdx.x * NTHR + threadIdx.x;
  if (i < 12288) {                       // tok_emb [96][128]
    int n = i >> 7, k = i & 127;
    wsb[WS_EMB + (k >> 3) * 768 + n * 8 + (k & 7)] = f2bf(tok_emb[i]);
    return;
  }
  i -= 12288;
  if (i < 262144) {                      // Wq,Wk,Wv,Wo: [4][128][128] each
    int tensor = i >> 16;
    int rem = i & 65535;
    int l = rem >> 14;
    int w = rem & 16383;
    int n = w >> 7, k = w & 127;
    const float* src = tensor == 0 ? Wq : tensor == 1 ? Wk : tensor == 2 ? Wv : Wo;
    wsb[WS_WQ + tensor * 65536 + l * 16384 + (k >> 3) * 1024 + n * 8 + (k & 7)] =
        f2bf(src[rem]);
    return;
  }
  i -= 262144;
  if (i < 262144) {                      // W1 [4][512][128]
    int l = i >> 16;
    int w = i & 65535;
    int n = w >> 7, k = w & 127;
    wsb[WS_W1 + l * 65536 + (k >> 3) * 4096 + n * 8 + (k & 7)] = f2bf(W1[i]);
    return;
  }
  i -= 262144;
  if (i < 262144) {                      // W2 [4][128][512]
    int l = i >> 16;
    int w = i & 65535;
    int n = w >> 9, k = w & 511;
    wsb[WS_W2 + l * 65536 + (k >> 3) * 1024 + n * 8 + (k & 7)] = f2bf(W2[i]);
  }
}

// LN on register-resident residual x[4] (x[n][r] = X^T[dim wave*16+lg*4+r][token 16n+lr]).
// Cross-wave stats via sPart[8][64] (s,s2). Writes normalized bf16 to sXn[64][136].
__device__ __forceinline__ void ln_regs(const f32x4* x, const float* __restrict__ g,
                                        const float* __restrict__ bb,
                                        short* __restrict__ sXn, float* __restrict__ sPart,
                                        int wave, int lr, int lg) {
  float s[4], s2[4];
#pragma unroll
  for (int n = 0; n < 4; ++n) {
    s[n] = (x[n][0] + x[n][1]) + (x[n][2] + x[n][3]);
    s2[n] = (x[n][0] * x[n][0] + x[n][1] * x[n][1]) +
            (x[n][2] * x[n][2] + x[n][3] * x[n][3]);
  }
#pragma unroll
  for (int n = 0; n < 4; ++n) {
    s[n] += __shfl_xor(s[n], 16, 64);  s[n] += __shfl_xor(s[n], 32, 64);
    s2[n] += __shfl_xor(s2[n], 16, 64); s2[n] += __shfl_xor(s2[n], 32, 64);
  }
  if (lg == 0) {
#pragma unroll
    for (int n = 0; n < 4; ++n) {
      float2 p; p.x = s[n]; p.y = s2[n];
      *(float2*)(sPart + (wave * 64 + 16 * n + lr) * 2) = p;
    }
  }
  __syncthreads();
  int dbase = wave * 16 + lg * 4;
  f32x4 g4 = *(const f32x4*)(g + dbase);
  f32x4 b4 = *(const f32x4*)(bb + dbase);
#pragma unroll
  for (int n = 0; n < 4; ++n) {
    float S = 0.f, S2 = 0.f;
#pragma unroll
    for (int w = 0; w < 8; ++w) {
      float2 p = *(const float2*)(sPart + (w * 64 + 16 * n + lr) * 2);
      S += p.x; S2 += p.y;
    }
    float mean = S * 0.0078125f;
    float rstd = rsqrtf(__builtin_fmaf(-mean, mean, S2 * 0.0078125f) + 1e-5f);
    f32x4 o;
#pragma unroll
    for (int c = 0; c < 4; ++c) o[c] = __builtin_fmaf((x[n][c] - mean) * rstd, g4[c], b4[c]);
    *(bf16x4*)(sXn + (16 * n + lr) * 136 + dbase) = pk4(o);
  }
  __syncthreads();
}

// One block per sequence, 8 waves, wave = head. Residual X^T in registers.
// LESSON (R3-R6): any waves_per_eu/min-blocks constraint >=4 makes the backend
// budget 64 arch VGPRs -> ~GB-scale spills. (512,2) is the only proven spill-free
// config (R2/R4). Occupancy stays ~24% (1 block/CU, 2 waves/SIMD) — so this round
// maximizes per-wave ILP instead: single-pass QKV (12 acc), batched attention
// MFMAs, unchunked FF (64 acc). LDS 88 KB.
__global__ __launch_bounds__(512, 2)
void lm_forward(const int* __restrict__ idx, const int* __restrict__ targets,
                const float* __restrict__ tok_emb, const float* __restrict__ pos_emb,
                const float* __restrict__ bo, const float* __restrict__ ln1_g,
                const float* __restrict__ ln1_b, const float* __restrict__ ln2_g,
                const float* __restrict__ ln2_b, const float* __restrict__ b1,
                const float* __restrict__ b2, const float* __restrict__ lnf_g,
                const float* __restrict__ lnf_b, const float* __restrict__ lm_b,
                const short* __restrict__ wsb, float* __restrict__ out,
                float* __restrict__ loss_part) {
  __shared__ __align__(16) short sXn[64 * 136];     // 17408 B
  __shared__ __align__(16) short sH[64 * 520];      // 66560 B (sAtt aliases head)
  __shared__ __align__(16) float sPart[8 * 64 * 2]; // 4096 B
  __shared__ float sTgt[64];                        // 256 B
  short* sAtt = sH;

  const int b = blockIdx.x;
  const int tid = threadIdx.x;
  const int wave = tid >> 6;
  const int lane = tid & 63;
  const int lr = lane & 15;
  const int lg = lane >> 4;
  const int dbase = wave * 16 + lg * 4;
  const f32x4 fz = {0.f, 0.f, 0.f, 0.f};
  const float KSC = 0.360673760f;                   // 0.25 * log2(e)

  // ---- embedding: residual regs ----
  f32x4 x[4];
#pragma unroll
  for (int n = 0; n < 4; ++n) {
    int t = 16 * n + lr;
    int tk = idx[b * 64 + t];
    f32x4 te = *(const f32x4*)(tok_emb + tk * 128 + dbase);
    f32x4 pe = *(const f32x4*)(pos_emb + t * 128 + dbase);
    x[n] = te + pe;
  }

#pragma unroll 1
  for (int l = 0; l < 4; ++l) {
    ln_regs(x, ln1_g + l * 128, ln1_b + l * 128, sXn, sPart, wave, lr, lg);

    // ---- QKV: single pass, 12 accumulators (max MFMA ILP) ----
    const short* wq = wsb + WS_WQ + l * 16384;
    const short* wk = wsb + WS_WK + l * 16384;
    const short* wv = wsb + WS_WV + l * 16384;
    bf16x4 qf[4], kf[4], vf[4];
    {
      f32x4 aq[4], ak[4], av[4];
#pragma unroll
      for (int n = 0; n < 4; ++n) { aq[n] = fz; ak[n] = fz; av[n] = fz; }
#pragma unroll
      for (int ks = 0; ks < 4; ++ks) {
        bf16x8 xf[4];
#pragma unroll
        for (int n = 0; n < 4; ++n)
          xf[n] = *(const bf16x8*)(sXn + (16 * n + lr) * 136 + ks * 32 + lg * 8);
        int wo_ = (ks * 4 + lg) * 1024 + (wave * 16 + lr) * 8;
        bf16x8 qw = *(const bf16x8*)(wq + wo_);
        bf16x8 kw = *(const bf16x8*)(wk + wo_);
        bf16x8 vw = *(const bf16x8*)(wv + wo_);
#pragma unroll
        for (int n = 0; n < 4; ++n) {
          aq[n] = MFMA32(qw, xf[n], aq[n]);
          ak[n] = MFMA32(kw, xf[n], ak[n]);
          av[n] = MFMA32(xf[n], vw, av[n]);
        }
      }
#pragma unroll
      for (int n = 0; n < 4; ++n) {
        qf[n] = pk4(aq[n] * KSC);
        kf[n] = pk4(ak[n]);
        vf[n] = pk4(av[n]);
      }
    }

    // ---- attention: batched MFMAs, in-register softmax, causal tile-skip ----
    {
      f32x4 sc[4][4];
      bf16x4 pf[4][4];
#pragma unroll
      for (int n = 0; n < 4; ++n)
#pragma unroll
        for (int m = 0; m <= n; ++m)
          sc[m][n] = MFMA16(kf[m], qf[n], fz);
      // mask diagonal tiles: key lg*4+r > query lr
#pragma unroll
      for (int n = 0; n < 4; ++n)
#pragma unroll
        for (int r = 0; r < 4; ++r)
          if (lg * 4 + r > lr) sc[n][n][r] = -1e30f;
      float mx[4], sm[4];
#pragma unroll
      for (int n = 0; n < 4; ++n) {
        float m0 = -1e30f;
#pragma unroll
        for (int m = 0; m <= n; ++m)
#pragma unroll
          for (int r = 0; r < 4; ++r) m0 = fmaxf(m0, sc[m][n][r]);
        mx[n] = m0;
      }
#pragma unroll
      for (int n = 0; n < 4; ++n) {
        mx[n] = fmaxf(mx[n], __shfl_xor(mx[n], 16, 64));
        mx[n] = fmaxf(mx[n], __shfl_xor(mx[n], 32, 64));
      }
#pragma unroll
      for (int n = 0; n < 4; ++n) {
        float s0 = 0.f;
#pragma unroll
        for (int m = 0; m <= n; ++m)
#pragma unroll
          for (int r = 0; r < 4; ++r) {
            float p = exp2f(sc[m][n][r] - mx[n]);
            sc[m][n][r] = p;
            s0 += p;
          }
        sm[n] = s0;
      }
#pragma unroll
      for (int n = 0; n < 4; ++n) {
        sm[n] += __shfl_xor(sm[n], 16, 64);
        sm[n] += __shfl_xor(sm[n], 32, 64);
      }
#pragma unroll
      for (int n = 0; n < 4; ++n) {
        float rinv = __builtin_amdgcn_rcpf(sm[n]);
#pragma unroll
        for (int m = 0; m <= n; ++m) pf[m][n] = pk4(sc[m][n] * rinv);
      }
      f32x4 ao[4];
#pragma unroll
      for (int n = 0; n < 4; ++n) ao[n] = fz;
#pragma unroll
      for (int m = 0; m < 4; ++m)
#pragma unroll
        for (int n = m; n < 4; ++n)
          ao[n] = MFMA16(vf[m], pf[m][n], ao[n]);
#pragma unroll
      for (int n = 0; n < 4; ++n)
        *(bf16x4*)(sAtt + (16 * n + lr) * 136 + dbase) = pk4(ao[n]);
    }
    __syncthreads();

    // ---- Wo + residual (in regs) ----
    {
      const short* wo = wsb + WS_WO + l * 16384;
      f32x4 ac[4];
#pragma unroll
      for (int n = 0; n < 4; ++n) ac[n] = fz;
#pragma unroll
      for (int ks = 0; ks < 4; ++ks) {
        bf16x8 wf = *(const bf16x8*)(wo + (ks * 4 + lg) * 1024 + (wave * 16 + lr) * 8);
#pragma unroll
        for (int n = 0; n < 4; ++n) {
          bf16x8 af = *(const bf16x8*)(sAtt + (16 * n + lr) * 136 + ks * 32 + lg * 8);
          ac[n] = MFMA32(wf, af, ac[n]);
        }
      }
      f32x4 bo4 = *(const f32x4*)(bo + l * 128 + dbase);
#pragma unroll
      for (int n = 0; n < 4; ++n) x[n] = x[n] + ac[n] + bo4;
    }

    ln_regs(x, ln2_g + l * 128, ln2_b + l * 128, sXn, sPart, wave, lr, lg);

    // ---- FF: unchunked hidden (64 acc FF1), single barrier pair ----
    {
      const short* w1 = wsb + WS_W1 + l * 65536;
      const short* w2 = wsb + WS_W2 + l * 65536;
      f32x4 a1[4][4];
#pragma unroll
      for (int g = 0; g < 4; ++g)
#pragma unroll
        for (int n = 0; n < 4; ++n) a1[g][n] = fz;
#pragma unroll
      for (int ks = 0; ks < 4; ++ks) {
        bf16x8 xf[4];
#pragma unroll
        for (int n = 0; n < 4; ++n)
          xf[n] = *(const bf16x8*)(sXn + (16 * n + lr) * 136 + ks * 32 + lg * 8);
#pragma unroll
        for (int g = 0; g < 4; ++g) {
          bf16x8 wf = *(const bf16x8*)(w1 + (ks * 4 + lg) * 4096 +
                                       (wave * 64 + g * 16 + lr) * 8);
#pragma unroll
          for (int n = 0; n < 4; ++n) a1[g][n] = MFMA32(wf, xf[n], a1[g][n]);
        }
      }
#pragma unroll
      for (int g = 0; g < 4; ++g) {
        f32x4 b1v = *(const f32x4*)(b1 + l * 512 + wave * 64 + g * 16 + lg * 4);
#pragma unroll
        for (int n = 0; n < 4; ++n) {
          f32x4 hv;
#pragma unroll
          for (int r = 0; r < 4; ++r) hv[r] = gelu1(a1[g][n][r] + b1v[r]);
          *(bf16x4*)(sH + (16 * n + lr) * 520 + wave * 64 + g * 16 + lg * 4) = pk4(hv);
        }
      }
      __syncthreads();
      f32x4 a2[4];
#pragma unroll
      for (int n = 0; n < 4; ++n) a2[n] = fz;
#pragma unroll
      for (int ks = 0; ks < 16; ++ks) {
        bf16x8 wf = *(const bf16x8*)(w2 + (ks * 4 + lg) * 1024 + (wave * 16 + lr) * 8);
#pragma unroll
        for (int n = 0; n < 4; ++n) {
          bf16x8 hf = *(const bf16x8*)(sH + (16 * n + lr) * 520 + ks * 32 + lg * 8);
          a2[n] = MFMA32(wf, hf, a2[n]);
        }
      }
      f32x4 b2v = *(const f32x4*)(b2 + l * 128 + dbase);
#pragma unroll
      for (int n = 0; n < 4; ++n) x[n] = x[n] + a2[n] + b2v;
    }
  }

  // ---- final LN ----
  ln_regs(x, lnf_g, lnf_b, sXn, sPart, wave, lr, lg);

  // ---- logits + CE partials (waves 0..5 cover 96 vocab cols) ----
  if (wave < 6) {
    f32x4 al[4];
#pragma unroll
    for (int n = 0; n < 4; ++n) al[n] = fz;
#pragma unroll
    for (int ks = 0; ks < 4; ++ks) {
      bf16x8 ef = *(const bf16x8*)(wsb + WS_EMB + (ks * 4 + lg) * 768 +
                                   (wave * 16 + lr) * 8);
#pragma unroll
      for (int n = 0; n < 4; ++n) {
        bf16x8 xf = *(const bf16x8*)(sXn + (16 * n + lr) * 136 + ks * 32 + lg * 8);
        al[n] = MFMA32(ef, xf, al[n]);
      }
    }
    f32x4 lb = *(const f32x4*)(lm_b + dbase);
#pragma unroll
    for (int n = 0; n < 4; ++n) {
      int t = 16 * n + lr;
      f32x4 v = al[n] + lb;
      *(f32x4*)(out + ((size_t)b * 64 + t) * 96 + dbase) = v;
      float mx = fmaxf(fmaxf(v[0], v[1]), fmaxf(v[2], v[3]));
      mx = fmaxf(mx, __shfl_xor(mx, 16, 64));
      mx = fmaxf(mx, __shfl_xor(mx, 32, 64));
      float es = __expf(v[0] - mx) + __expf(v[1] - mx) +
                 __expf(v[2] - mx) + __expf(v[3] - mx);
      es += __shfl_xor(es, 16, 64);
      es += __shfl_xor(es, 32, 64);
      if (lg == 0) {
        float2 p; p.x = mx; p.y = es;
        *(float2*)(sPart + (wave * 64 + t) * 2) = p;
      }
      int cgt = targets[b * 64 + t];
      if ((cgt >> 4) == wave && ((cgt >> 2) & 3) == lg) {
#pragma unroll
        for (int r = 0; r < 4; ++r)
          if ((cgt & 3) == r) sTgt[t] = v[r];
      }
    }
  }
  __syncthreads();
  if (wave == 0) {
    float mxw[6], esw[6];
#pragma unroll
    for (int w = 0; w < 6; ++w) {
      float2 p = *(const float2*)(sPart + (w * 64 + lane) * 2);
      mxw[w] = p.x; esw[w] = p.y;
    }
    float MX = mxw[0];
#pragma unroll
    for (int w = 1; w < 6; ++w) MX = fmaxf(MX, mxw[w]);
    float SUM = 0.f;
#pragma unroll
    for (int w = 0; w < 6; ++w) SUM += esw[w] * __expf(mxw[w] - MX);
    float lt = MX + logf(SUM) - sTgt[lane];
#pragma unroll
    for (int m = 32; m >= 1; m >>= 1) lt += __shfl_xor(lt, m, 64);
    if (lane == 0) loss_part[b] = lt;
  }
}

__global__ void loss_reduce(const float* __restrict__ loss_part, float* __restrict__ out_loss) {
  __shared__ float red[256];
  int t = threadIdx.x;
  float s = 0.f;
  for (int i = t; i < 4096; i += 256) s += loss_part[i];
  red[t] = s;
  __syncthreads();
  for (int k = 128; k >= 1; k >>= 1) {
    if (t < k) red[t] += red[t + k];
    __syncthreads();
  }
  if (t == 0) out_loss[0] = red[0] * (1.f / 262144.f);
}

extern "C" void kernel_launch(void* const* d_in, const int* in_sizes, int n_in,
                              void* d_out, int out_size, void* d_ws, size_t ws_size,
                              hipStream_t stream) {
  (void)in_sizes; (void)n_in; (void)ws_size;
  const int* idx      = (const int*)d_in[0];
  const int* targets  = (const int*)d_in[1];
  const float* tok_emb = (const float*)d_in[2];
  const float* pos_emb = (const float*)d_in[3];
  const float* Wq = (const float*)d_in[4];
  const float* Wk = (const float*)d_in[5];
  const float* Wv = (const float*)d_in[6];
  const float* Wo = (const float*)d_in[7];
  const float* bo = (const float*)d_in[8];
  const float* ln1_g = (const float*)d_in[9];
  const float* ln1_b = (const float*)d_in[10];
  const float* ln2_g = (const float*)d_in[11];
  const float* ln2_b = (const float*)d_in[12];
  const float* W1 = (const float*)d_in[13];
  const float* b1 = (const float*)d_in[14];
  const float* W2 = (const float*)d_in[15];
  const float* b2 = (const float*)d_in[16];
  const float* lnf_g = (const float*)d_in[17];
  const float* lnf_b = (const float*)d_in[18];
  const float* lm_b = (const float*)d_in[19];

  short* wsb = (short*)d_ws;
  float* loss_part = (float*)((char*)d_ws + (size_t)WS_END * 2);
  float* out = (float*)d_out;

  prep_weights<<<1560, NTHR, 0, stream>>>(tok_emb, Wq, Wk, Wv, Wo, W1, W2, wsb);
  lm_forward<<<4096, NTHR, 0, stream>>>(idx, targets, tok_emb, pos_emb, bo,
                                        ln1_g, ln1_b, ln2_g, ln2_b, b1, b2,
                                        lnf_g, lnf_b, lm_b, wsb, out, loss_part);
  loss_reduce<<<1, 256, 0, stream>>>(loss_part, out + (out_size - 1));
}